// Round 11
// baseline (690.896 us; speedup 1.0000x reference)
//
// GCNTox21 fused pipeline — MI355X/gfx950.  R11: k_msg7 = 4 ch/thread with
// nodes PARALLEL within block (2 waves/edge-visit instead of 4; total wave
// count unchanged — R8 cut waves 4x and died).  __launch_bounds__(256,2) lets
// the 64-reg weight array stay resident (R10's VGPR=28 proved the compiler
// was re-loading weights in-loop).  k_canon dropped (pool reads raw batch);
// encoders merged.  GEMMs = R10 (proven).
#include <hip/hip_runtime.h>
#include <hip/hip_bf16.h>

typedef unsigned int  uint;
typedef unsigned short ushort;
typedef float  f32x2  __attribute__((ext_vector_type(2)));
typedef float  f32x4  __attribute__((ext_vector_type(4)));
typedef __bf16 bf16x8 __attribute__((ext_vector_type(8)));

#define DEV static __device__ __forceinline__

DEV float  b2f(ushort b){ return __uint_as_float(((uint)b) << 16); }
DEV float  lo2f(uint u){ return __uint_as_float(u << 16); }
DEV float  hi2f(uint u){ return __uint_as_float(u & 0xffff0000u); }
DEV ushort f2b(float f){           // RNE float->bf16
  uint u = __float_as_uint(f);
  u += 0x7fffu + ((u >> 16) & 1u);
  return (ushort)(u >> 16);
}
DEV uint pk2(float a, float b){ return (uint)f2b(a) | ((uint)f2b(b) << 16); }
DEV void unpack8(uint4 v, float* f){
  f[0]=lo2f(v.x); f[1]=hi2f(v.x); f[2]=lo2f(v.y); f[3]=hi2f(v.y);
  f[4]=lo2f(v.z); f[5]=hi2f(v.z); f[6]=lo2f(v.w); f[7]=hi2f(v.w);
}
DEV int ld_idx(const void* p, int flag, long long i){
  return flag ? ((const int*)p)[i] : (int)((const long long*)p)[i];
}
DEV int clampi(int v, int lo, int hi){ return v < lo ? lo : (v > hi ? hi : v); }

// async 16B global -> LDS (DMA).  LDS dest = wave-uniform base + lane*16.
DEV void ld16(const ushort* g, ushort* l){
  __builtin_amdgcn_global_load_lds(
      (const __attribute__((address_space(1))) void*)g,
      (__attribute__((address_space(3))) void*)l, 16, 0, 0);
}

// ---------- merged probes ----------
__global__ void k_probes(const uint* __restrict__ ei, const uint* __restrict__ xw,
                         int* __restrict__ iflag, int* __restrict__ fflag){
  __shared__ int anyI, cntF;
  if (threadIdx.x == 0){ anyI = 0; cntF = 0; }
  __syncthreads();
  int li = 0, lc = 0;
  for (int i = threadIdx.x; i < 1024; i += 256){
    if (ei[2*i + 1] != 0u) li = 1;            // int64 => odd words all 0
    float f = fabsf(__uint_as_float(xw[i]));  // fp32 N(0,1) words decode sane
    if (f > 1e-6f && f < 1e6f) lc++;
  }
  if (li) atomicOr(&anyI, 1);
  atomicAdd(&cntF, lc);
  __syncthreads();
  if (threadIdx.x == 0){ *iflag = anyI; *fflag = (2*cntF > 1024) ? 1 : 0; }
}

struct CvtTab { const void* src[8]; ushort* dst[8]; int n[8]; int bstart[8]; int nseg; };
__global__ __launch_bounds__(256) void k_cvt_batch(CvtTab tab, const int* __restrict__ flag){
  int b = blockIdx.x;
  int s = tab.nseg - 1;
  for (int i = 1; i < tab.nseg; i++) if (b < tab.bstart[i]){ s = i - 1; break; }
  int rel = b - tab.bstart[s];
  const void* sp = tab.src[s];
  ushort* d = tab.dst[s];
  int f = *flag;
  int end = tab.n[s]; int cap = rel*8192 + 8192; if (cap < end) end = cap;
  for (int i = rel*8192 + threadIdx.x; i < end; i += 256)
    d[i] = f ? f2b(((const float*)sp)[i]) : ((const ushort*)sp)[i];
}

struct SmallTab { const void* src[24]; int doff[24]; int n[24]; };
__global__ __launch_bounds__(256) void k_cvt_small(SmallTab tab, const int* __restrict__ flag,
    ushort* __restrict__ base, int cnt){
  int b = blockIdx.x;
  if (b >= cnt) return;
  int f = *flag;
  const void* s = tab.src[b];
  ushort* d = base + tab.doff[b];
  for (int i = threadIdx.x; i < tab.n[b]; i += 256)
    d[i] = f ? f2b(((const float*)s)[i]) : ((const ushort*)s)[i];
}

// ---------- CSR build over dst ----------
__global__ __launch_bounds__(256) void k_count(const void* __restrict__ ei,
    const int* __restrict__ flag, int* __restrict__ cnt, int E, int N){
  int e = blockIdx.x*256 + threadIdx.x;
  if (e >= E) return;
  int d = clampi(ld_idx(ei, *flag, (long long)E + e), 0, N-1);
  atomicAdd(&cnt[d], 1);
}

__global__ __launch_bounds__(1024) void k_scan(const int* __restrict__ deg, int* __restrict__ rp, int n){
  __shared__ int part[1024];
  int t = threadIdx.x;
  int chunk = (n + 1023) >> 10;
  int base = t * chunk;
  int s = 0;
  for (int i = 0; i < chunk; i++){ int j = base + i; if (j < n) s += deg[j]; }
  part[t] = s;
  __syncthreads();
  for (int off = 1; off < 1024; off <<= 1){
    int v = (t >= off) ? part[t - off] : 0;
    __syncthreads();
    part[t] += v;
    __syncthreads();
  }
  int run = part[t] - s;
  for (int i = 0; i < chunk; i++){ int j = base + i; if (j < n){ rp[j] = run; run += deg[j]; } }
  if (t == 1023) rp[n] = part[1023];
}

__global__ __launch_bounds__(256) void k_fill(const void* __restrict__ ei,
    const int* __restrict__ flag, const int* __restrict__ rp, int* __restrict__ fill,
    int2* __restrict__ cpair, int E, int N){
  int e = blockIdx.x*256 + threadIdx.x;
  if (e >= E) return;
  int f = *flag;
  int s = clampi(ld_idx(ei, f, e), 0, N-1);
  int d = clampi(ld_idx(ei, f, (long long)E + e), 0, N-1);
  int pos = clampi(rp[d] + atomicAdd(&fill[d], 1), 0, E-1);
  cpair[pos] = make_int2(s, e);
}

// ---------- merged encoders: edge blocks [0, EB) then node blocks ----------
__global__ __launch_bounds__(256) void k_enc(const void* __restrict__ ea,
    const ushort* __restrict__ eew, const ushort* __restrict__ eeb,
    const void* __restrict__ x, const ushort* __restrict__ nw,
    const ushort* __restrict__ nb_, const int* __restrict__ fflag,
    float* __restrict__ eh, ushort* __restrict__ h, int E, int N, int EB){
  int f = *fflag;
  int t = threadIdx.x;
  if ((int)blockIdx.x < EB){
    __shared__ float ws[128];
    __shared__ float bs[16];
    if (t < 128) ws[t] = b2f(eew[t]);
    if (t < 16)  bs[t] = b2f(eeb[t]);
    __syncthreads();
    int e = blockIdx.x*256 + t;
    if (e >= E) return;
    float a[8];
    if (f){
      const float4* ap = (const float4*)((const float*)ea + (size_t)e*8);
      float4 v0 = ap[0], v1 = ap[1];
      a[0]=v0.x; a[1]=v0.y; a[2]=v0.z; a[3]=v0.w;
      a[4]=v1.x; a[5]=v1.y; a[6]=v1.z; a[7]=v1.w;
    } else {
      uint4 av = *(const uint4*)((const ushort*)ea + (size_t)e*8);
      unpack8(av, a);
    }
    float o[16];
    #pragma unroll
    for (int c = 0; c < 16; c++){
      float s = bs[c];
      #pragma unroll
      for (int j = 0; j < 8; j++) s += a[j]*ws[c*8+j];
      o[c] = fmaxf(s, 0.f);
    }
    f32x4* op = (f32x4*)(eh + (size_t)e*16);
    #pragma unroll
    for (int q4 = 0; q4 < 4; q4++){
      f32x4 v = {o[q4*4+0], o[q4*4+1], o[q4*4+2], o[q4*4+3]};
      op[q4] = v;
    }
  } else {
    __shared__ float xs[4][32];
    int nb = (blockIdx.x - EB)*4;
    if (t < 128){
      int ni = t >> 5, ci = t & 31;
      int n = nb + ni; if (n >= N) n = N - 1;
      xs[ni][ci] = f ? ((const float*)x)[(size_t)n*32 + ci]
                     : b2f(((const ushort*)x)[(size_t)n*32 + ci]);
    }
    __syncthreads();
    const uint4* wp = (const uint4*)(nw + (size_t)t*32);
    float wr[32];
    unpack8(wp[0], wr); unpack8(wp[1], wr+8); unpack8(wp[2], wr+16); unpack8(wp[3], wr+24);
    float bv = b2f(nb_[t]);
    #pragma unroll
    for (int ni = 0; ni < 4; ni++){
      int n = nb + ni;
      if (n >= N) break;
      float s = bv;
      #pragma unroll
      for (int k = 0; k < 32; k++) s += xs[ni][k]*wr[k];
      h[(size_t)n*256 + t] = f2b(fmaxf(s, 0.f));
    }
  }
}

// ---------- LDS-staged 128x128 GEMM: P/Q producer (R9, unchanged) ----------
__global__ __launch_bounds__(256) void k_gemm_pq_lds(const ushort* __restrict__ A,
    const ushort* __restrict__ w1, int M, int Nc,
    ushort* __restrict__ P, ushort* __restrict__ Q){
  __shared__ ushort As[128*32];
  __shared__ ushort Bs[128*32];
  const int t = threadIdx.x;
  const int lane = t & 63;
  const int wv = t >> 6;
  const int m0 = blockIdx.x*128;
  const int yc = Nc >> 7;
  const int isQ = (int)blockIdx.y >= yc;
  const int n0 = (isQ ? blockIdx.y - yc : blockIdx.y)*128;
  const ushort* W = w1 + (isQ ? 256 : 0);
  ushort* C = isQ ? Q : P;
  const int lr = lane & 15;
  const int qq = lane >> 4;
  int srow0 = t >> 2,         sq0 = t & 3;
  int srow1 = (256 + t) >> 2, sq1 = t & 3;
  int ga0 = m0 + srow0; if (ga0 >= M) ga0 = M - 1;
  int ga1 = m0 + srow1; if (ga1 >= M) ga1 = M - 1;
  f32x4 acc[2][8];
  #pragma unroll
  for (int f = 0; f < 2; f++)
    #pragma unroll
    for (int j = 0; j < 8; j++) acc[f][j] = {0.f,0.f,0.f,0.f};
  for (int k0 = 0; k0 < 256; k0 += 32){
    ld16(A + (size_t)ga0*256 + k0 + sq0*8, &As[(size_t)t*8]);
    ld16(A + (size_t)ga1*256 + k0 + sq1*8, &As[(size_t)(256+t)*8]);
    ld16(W + (size_t)(n0 + srow0)*528 + k0 + sq0*8, &Bs[(size_t)t*8]);
    ld16(W + (size_t)(n0 + srow1)*528 + k0 + sq1*8, &Bs[(size_t)(256+t)*8]);
    __syncthreads();
    bf16x8 a0 = *(const bf16x8*)&As[(wv*32 + lr)*32 + qq*8];
    bf16x8 a1 = *(const bf16x8*)&As[(wv*32 + 16 + lr)*32 + qq*8];
    #pragma unroll
    for (int j = 0; j < 8; j++){
      bf16x8 b = *(const bf16x8*)&Bs[(j*16 + lr)*32 + qq*8];
      acc[0][j] = __builtin_amdgcn_mfma_f32_16x16x32_bf16(a0, b, acc[0][j], 0, 0, 0);
      acc[1][j] = __builtin_amdgcn_mfma_f32_16x16x32_bf16(a1, b, acc[1][j], 0, 0, 0);
    }
    __syncthreads();
  }
  #pragma unroll
  for (int f = 0; f < 2; f++){
    #pragma unroll
    for (int r = 0; r < 4; r++){
      int row = m0 + wv*32 + f*16 + qq*4 + r;
      if (row >= M) continue;
      #pragma unroll
      for (int j = 0; j < 8; j++)
        C[(size_t)row*Nc + n0 + j*16 + lr] = f2b(acc[f][j][r]);
    }
  }
}

// ---------- LDS-staged 64x128 GEMM + bias + deg-mask + BN + relu (R10) ----------
__global__ __launch_bounds__(256) void k_gemm_bn64(const ushort* __restrict__ A, int lda,
    const ushort* __restrict__ W, int ldb, int M, int Nc, int K,
    const ushort* __restrict__ bias, const ushort* __restrict__ g, const ushort* __restrict__ bb,
    const ushort* __restrict__ rm, const ushort* __restrict__ rv,
    const int* __restrict__ rp, ushort* __restrict__ H){
  __shared__ ushort As[64*32];
  __shared__ ushort Bs[128*32];
  const int t = threadIdx.x;
  const int lane = t & 63;
  const int wv = t >> 6;
  const int m0 = blockIdx.x*64;
  const int n0 = blockIdx.y*128;
  const int lr = lane & 15;
  const int qq = lane >> 4;
  int srowA = t >> 2, sqA = t & 3;
  int ga = m0 + srowA; if (ga >= M) ga = M - 1;
  int srowB0 = t >> 2,        srowB1 = 64 + (t >> 2);
  f32x4 acc[8];
  #pragma unroll
  for (int j = 0; j < 8; j++) acc[j] = {0.f,0.f,0.f,0.f};
  for (int k0 = 0; k0 < K; k0 += 32){
    ld16(A + (size_t)ga*lda + k0 + sqA*8, &As[(size_t)t*8]);
    ld16(W + (size_t)(n0 + srowB0)*ldb + k0 + sqA*8, &Bs[(size_t)t*8]);
    ld16(W + (size_t)(n0 + srowB1)*ldb + k0 + sqA*8, &Bs[(size_t)(256+t)*8]);
    __syncthreads();
    bf16x8 a = *(const bf16x8*)&As[(wv*16 + lr)*32 + qq*8];
    #pragma unroll
    for (int j = 0; j < 8; j++){
      bf16x8 b = *(const bf16x8*)&Bs[(j*16 + lr)*32 + qq*8];
      acc[j] = __builtin_amdgcn_mfma_f32_16x16x32_bf16(a, b, acc[j], 0, 0, 0);
    }
    __syncthreads();
  }
  float bi[8], sc[8], sh[8];
  #pragma unroll
  for (int j = 0; j < 8; j++){
    int col = n0 + j*16 + lr;
    bi[j] = b2f(bias[col]);
    sc[j] = b2f(g[col]) * rsqrtf(b2f(rv[col]) + 1e-5f);
    sh[j] = b2f(bb[col]) - b2f(rm[col]) * sc[j];
  }
  #pragma unroll
  for (int r = 0; r < 4; r++){
    int row = m0 + wv*16 + qq*4 + r;
    if (row >= M) continue;
    int empty = (rp[row+1] - rp[row] == 0);
    #pragma unroll
    for (int j = 0; j < 8; j++){
      float v = acc[j][r] + bi[j];
      if (empty) v = 0.f;
      H[(size_t)row*Nc + n0 + j*16 + lr] = f2b(fmaxf(v*sc[j] + sh[j], 0.f));
    }
  }
}

// ---------- per-node edge aggregation v7 ----------
// 4 channels/thread; nodes PARALLEL within block: thread group [ni*TPN,
// (ni+1)*TPN) owns node nb+ni (TPN = C/4; groups are wave-aligned).
// Each edge visited by C/256 waves (2 for C=512) instead of 4.  2-edge ILP
// unroll.  No barriers/LDS.  MU may alias P (read-before-write per thread).
template<int C>
__global__ __launch_bounds__(256, 2) void k_msg7(const ushort* P, const ushort* __restrict__ Q,
    const float* __restrict__ eh, const ushort* __restrict__ w1, const ushort* __restrict__ b1,
    const int* __restrict__ rp, const int2* __restrict__ cpair,
    ushort* MU, int N){
  const int TPN = C/4;            // threads per node
  const int NPB = 256/TPN;        // nodes per block
  int t = threadIdx.x;
  int ni = t / TPN;
  int tl = t - ni*TPN;
  int n = blockIdx.x*NPB + ni;
  if (n >= N) return;
  int c0 = tl*4;
  f32x2 w01[16], w23[16];
  {
    float a0[16], a1[16], a2[16], a3[16];
    const uint4* wp0 = (const uint4*)(w1 + (size_t)(c0+0)*528 + 512);
    const uint4* wp1 = (const uint4*)(w1 + (size_t)(c0+1)*528 + 512);
    const uint4* wp2 = (const uint4*)(w1 + (size_t)(c0+2)*528 + 512);
    const uint4* wp3 = (const uint4*)(w1 + (size_t)(c0+3)*528 + 512);
    unpack8(wp0[0], a0); unpack8(wp0[1], a0+8);
    unpack8(wp1[0], a1); unpack8(wp1[1], a1+8);
    unpack8(wp2[0], a2); unpack8(wp2[1], a2+8);
    unpack8(wp3[0], a3); unpack8(wp3[1], a3+8);
    #pragma unroll
    for (int j = 0; j < 16; j++){
      w01[j].x = a0[j]; w01[j].y = a1[j];
      w23[j].x = a2[j]; w23[j].y = a3[j];
    }
  }
  uint2 bw = *(const uint2*)(b1 + c0);
  uint2 pw = *(const uint2*)(P + (size_t)n*C + c0);
  f32x2 pre01 = { lo2f(pw.x) + lo2f(bw.x), hi2f(pw.x) + hi2f(bw.x) };
  f32x2 pre23 = { lo2f(pw.y) + lo2f(bw.y), hi2f(pw.y) + hi2f(bw.y) };
  const int i0 = rp[n], i1 = rp[n+1];
  f32x2 a01 = {0.f,0.f}, a23 = {0.f,0.f};
  f32x2 b01 = {0.f,0.f}, b23 = {0.f,0.f};
  int i = i0;
  for (; i + 2 <= i1; i += 2){
    int2 p0 = cpair[i];
    int2 p1 = cpair[i+1];
    uint2 q0 = *(const uint2*)(Q + (size_t)p0.x*C + c0);
    uint2 q1 = *(const uint2*)(Q + (size_t)p1.x*C + c0);
    const f32x4* e0p = (const f32x4*)(eh + (size_t)p0.y*16);
    const f32x4* e1p = (const f32x4*)(eh + (size_t)p1.y*16);
    f32x4 ea0 = e0p[0], ea1 = e0p[1], ea2 = e0p[2], ea3 = e0p[3];
    f32x4 eb0 = e1p[0], eb1 = e1p[1], eb2 = e1p[2], eb3 = e1p[3];
    float ef0[16] = {ea0.x,ea0.y,ea0.z,ea0.w, ea1.x,ea1.y,ea1.z,ea1.w,
                     ea2.x,ea2.y,ea2.z,ea2.w, ea3.x,ea3.y,ea3.z,ea3.w};
    float ef1[16] = {eb0.x,eb0.y,eb0.z,eb0.w, eb1.x,eb1.y,eb1.z,eb1.w,
                     eb2.x,eb2.y,eb2.z,eb2.w, eb3.x,eb3.y,eb3.z,eb3.w};
    f32x2 d01 = { pre01.x + lo2f(q0.x), pre01.y + hi2f(q0.x) };
    f32x2 d23 = { pre23.x + lo2f(q0.y), pre23.y + hi2f(q0.y) };
    f32x2 g01 = { pre01.x + lo2f(q1.x), pre01.y + hi2f(q1.x) };
    f32x2 g23 = { pre23.x + lo2f(q1.y), pre23.y + hi2f(q1.y) };
    #pragma unroll
    for (int j = 0; j < 16; j++){
      f32x2 e0v = {ef0[j], ef0[j]};
      f32x2 e1v = {ef1[j], ef1[j]};
      d01 += w01[j] * e0v; d23 += w23[j] * e0v;
      g01 += w01[j] * e1v; g23 += w23[j] * e1v;
    }
    a01.x += fmaxf(d01.x, 0.f); a01.y += fmaxf(d01.y, 0.f);
    a23.x += fmaxf(d23.x, 0.f); a23.y += fmaxf(d23.y, 0.f);
    b01.x += fmaxf(g01.x, 0.f); b01.y += fmaxf(g01.y, 0.f);
    b23.x += fmaxf(g23.x, 0.f); b23.y += fmaxf(g23.y, 0.f);
  }
  if (i < i1){
    int2 p0 = cpair[i];
    uint2 q0 = *(const uint2*)(Q + (size_t)p0.x*C + c0);
    const f32x4* e0p = (const f32x4*)(eh + (size_t)p0.y*16);
    f32x4 ea0 = e0p[0], ea1 = e0p[1], ea2 = e0p[2], ea3 = e0p[3];
    float ef0[16] = {ea0.x,ea0.y,ea0.z,ea0.w, ea1.x,ea1.y,ea1.z,ea1.w,
                     ea2.x,ea2.y,ea2.z,ea2.w, ea3.x,ea3.y,ea3.z,ea3.w};
    f32x2 d01 = { pre01.x + lo2f(q0.x), pre01.y + hi2f(q0.x) };
    f32x2 d23 = { pre23.x + lo2f(q0.y), pre23.y + hi2f(q0.y) };
    #pragma unroll
    for (int j = 0; j < 16; j++){
      f32x2 e0v = {ef0[j], ef0[j]};
      d01 += w01[j] * e0v; d23 += w23[j] * e0v;
    }
    a01.x += fmaxf(d01.x, 0.f); a01.y += fmaxf(d01.y, 0.f);
    a23.x += fmaxf(d23.x, 0.f); a23.y += fmaxf(d23.y, 0.f);
  }
  int cnt = i1 - i0;
  float inv = (cnt > 0) ? 1.f/(float)cnt : 0.f;
  uint2 outw = { pk2((a01.x + b01.x)*inv, (a01.y + b01.y)*inv),
                 pk2((a23.x + b23.x)*inv, (a23.y + b23.y)*inv) };
  *(uint2*)(MU + (size_t)n*C + c0) = outw;
}

// ---------- pooling + FC + sigmoid (reads raw batch via iflag) ----------
__global__ __launch_bounds__(128) void k_pool(const ushort* __restrict__ h, const void* __restrict__ batch,
    const int* __restrict__ iflag, const ushort* __restrict__ fw, const ushort* __restrict__ fb,
    const int* __restrict__ fflag, void* __restrict__ out, int N){
  int g = blockIdx.x, t = threadIdx.x;
  int ifl = *iflag;
  int lo = 0, hi = N;
  while (lo < hi){ int mid = (lo+hi) >> 1; if (ld_idx(batch, ifl, mid) <  g) lo = mid+1; else hi = mid; }
  int s0 = lo;
  hi = N;
  while (lo < hi){ int mid = (lo+hi) >> 1; if (ld_idx(batch, ifl, mid) <= g) lo = mid+1; else hi = mid; }
  int s1 = lo;
  float s = 0.f;
  for (int i = s0; i < s1; i++) s += b2f(h[(size_t)i*128 + t]);
  int cnt = s1 - s0;
  __shared__ float ps[128];
  ps[t] = s / (float)(cnt > 0 ? cnt : 1);
  __syncthreads();
  if (t < 12){
    float z = b2f(fb[t]);
    for (int j = 0; j < 128; j++) z += ps[j]*b2f(fw[t*128 + j]);
    float r = 1.f/(1.f + expf(-z));
    if (*fflag) ((float*)out)[g*12 + t] = r;
    else        ((ushort*)out)[g*12 + t] = f2b(r);
  }
}

__global__ __launch_bounds__(256) void k_sentinel(ushort* __restrict__ out, int n){
  int i = blockIdx.x*256 + threadIdx.x;
  if (i < n) out[i] = 0x3F00;
}

extern "C" void kernel_launch(void* const* d_in, const int* in_sizes, int n_in,
                              void* d_out, int out_size, void* d_ws, size_t ws_size,
                              hipStream_t stream){
  const void* x_raw   = d_in[0];
  const void* ei_raw  = d_in[1];
  const void* ea_raw  = d_in[2];
  const void* ba_raw  = d_in[3];
  (void)n_in;

  const int N = in_sizes[3];        // 20000
  const int E = in_sizes[1] / 2;    // 200000
  const int G = out_size / 12;      // 512

  // ---- workspace plan ----
  char* base = (char*)d_ws;
  size_t off = 0;
  auto alloc = [&](size_t bytes)->char*{
    char* p = base + off;
    off = (off + bytes + 255) & ~(size_t)255;
    return p;
  };
  int* iflag    = (int*)alloc(256);
  int* fflag    = (int*)alloc(256);
  int* deg      = (int*)alloc((size_t)N*4);
  int* fill     = (int*)alloc((size_t)N*4);   // contiguous after deg (one memset)
  size_t memset_bytes = (size_t)((char*)fill - (char*)deg) + (size_t)N*4;
  int* rp       = (int*)alloc((size_t)(N+1)*4);
  int2* cpair   = (int2*)alloc((size_t)E*8);
  ushort* new_c = (ushort*)alloc(8192*2);
  ushort* w1c[3], *w2c[3];
  const int w1n[3] = {512*528, 512*528, 256*528};
  const int w2n[3] = {256*512, 256*512, 128*256};
  for (int i = 0; i < 3; i++) w1c[i] = (ushort*)alloc((size_t)w1n[i]*2);
  for (int i = 0; i < 3; i++) w2c[i] = (ushort*)alloc((size_t)w2n[i]*2);
  ushort* smallp = (ushort*)alloc(8192*2);
  float*  e_h32 = (float*)alloc((size_t)E*16*4);    // 12.8 MB, pre-unpacked f32
  ushort* h     = (ushort*)alloc((size_t)N*256*2);
  ushort* Q     = (ushort*)alloc((size_t)N*512*2);
  ushort* PM    = (ushort*)alloc((size_t)N*512*2);

  if (off > ws_size){
    k_sentinel<<<(out_size + 255)/256, 256, 0, stream>>>((ushort*)d_out, out_size);
    return;
  }

  // ---- probes + CSR ----
  k_probes<<<1, 256, 0, stream>>>((const uint*)ei_raw, (const uint*)x_raw, iflag, fflag);
  hipMemsetAsync(deg, 0, memset_bytes, stream);
  k_count<<<(E + 255)/256, 256, 0, stream>>>(ei_raw, iflag, deg, E, N);
  k_scan<<<1, 1024, 0, stream>>>(deg, rp, N);
  k_fill<<<(E + 255)/256, 256, 0, stream>>>(ei_raw, iflag, rp, fill, cpair, E, N);

  // ---- batched weight conversion (w1 x3, w2 x3, ne_w) ----
  CvtTab ct; ct.nseg = 7;
  const void* csrcs[7] = {d_in[8], d_in[16], d_in[24], d_in[10], d_in[18], d_in[26], d_in[6]};
  ushort* cdsts[7]     = {w1c[0],  w1c[1],   w1c[2],   w2c[0],   w2c[1],   w2c[2],   new_c};
  const int cns[7]     = {w1n[0],  w1n[1],   w1n[2],   w2n[0],   w2n[1],   w2n[2],   8192};
  int bacc = 0;
  for (int i = 0; i < 7; i++){
    ct.src[i] = csrcs[i]; ct.dst[i] = cdsts[i]; ct.n[i] = cns[i];
    ct.bstart[i] = bacc; bacc += (cns[i] + 8191)/8192;
  }
  k_cvt_batch<<<bacc, 256, 0, stream>>>(ct, fflag);

  // ---- small vectors packed ----
  SmallTab tab;
  int scount = 0, spos = 0;
  auto addsmall = [&](int di, int n)->int{
    int p = spos;
    tab.src[scount] = d_in[di]; tab.doff[scount] = spos; tab.n[scount] = n;
    spos += n; scount++;
    return p;
  };
  int pos_eew  = addsmall(4, 128);
  int pos_eeb  = addsmall(5, 16);
  int pos_neb  = addsmall(7, 256);
  int pos_b1[3], pos_b2[3], pos_g[3], pos_bb[3], pos_m[3], pos_v[3];
  const int b1n[3] = {512,512,256}, b2n[3] = {256,256,128}, bnn[3] = {256,256,128};
  for (int i = 0; i < 3; i++){
    int di = 8 + 8*i;
    pos_b1[i] = addsmall(di+1, b1n[i]);
    pos_b2[i] = addsmall(di+3, b2n[i]);
    pos_g[i]  = addsmall(di+4, bnn[i]);
    pos_bb[i] = addsmall(di+5, bnn[i]);
    pos_m[i]  = addsmall(di+6, bnn[i]);
    pos_v[i]  = addsmall(di+7, bnn[i]);
  }
  int pos_fcw = addsmall(32, 12*128);
  int pos_fcb = addsmall(33, 12);
  k_cvt_small<<<scount, 256, 0, stream>>>(tab, fflag, smallp, scount);

  // ---- merged encoders ----
  int EB = (E + 255)/256;
  int NB = (N + 3)/4;
  k_enc<<<EB + NB, 256, 0, stream>>>(ea_raw, smallp + pos_eew, smallp + pos_eeb,
                                     x_raw, new_c, smallp + pos_neb, fflag,
                                     e_h32, h, E, N, EB);

  // ---- 3 conv layers ----
  const int Cch[3] = {512, 512, 256};
  const int Od[3]  = {256, 256, 128};
  for (int i = 0; i < 3; i++){
    dim3 g1((N + 127)/128, 2*(Cch[i]/128));
    k_gemm_pq_lds<<<g1, 256, 0, stream>>>(h, w1c[i], N, Cch[i], PM, Q);
    if (i < 2){
      dim3 gm((N + 1)/2);   // NPB=2 for C=512
      k_msg7<512><<<gm, 256, 0, stream>>>(PM, Q, e_h32, w1c[i], smallp + pos_b1[i], rp, cpair, PM, N);
    } else {
      dim3 gm((N + 3)/4);   // NPB=4 for C=256
      k_msg7<256><<<gm, 256, 0, stream>>>(PM, Q, e_h32, w1c[i], smallp + pos_b1[i], rp, cpair, PM, N);
    }
    dim3 g2((N + 63)/64, Od[i]/128 > 0 ? Od[i]/128 : 1);
    k_gemm_bn64<<<g2, 256, 0, stream>>>(PM, Cch[i], w2c[i], Cch[i], N, Od[i], Cch[i],
                                        smallp + pos_b2[i], smallp + pos_g[i], smallp + pos_bb[i],
                                        smallp + pos_m[i],  smallp + pos_v[i], rp, h);
  }

  // ---- mean pool + FC + sigmoid ----
  k_pool<<<G, 128, 0, stream>>>(h, ba_raw, iflag, smallp + pos_fcw, smallp + pos_fcb, fflag, d_out, N);
}

// Round 12
// 501.305 us; speedup vs baseline: 1.3782x; 1.3782x over previous
//
// GCNTox21 fused pipeline — MI355X/gfx950.  R12: k_msg4 reverted to R10's
// exact known-good form (2 nodes/block, 2ch/thread, VGPR 28 => 8 waves/SIMD;
// 4ch/thread variants hit the 64-VGPR occupancy cliff twice — R8/R11).
// Launch chain cut 21 -> 14 dispatches: zero+probe fused; cvt_small removed
// (all small params read raw via fflag); fill+weight-cvt+encoders fused into
// one range-partitioned mega-kernel.  GEMMs = R10 (proven).
#include <hip/hip_runtime.h>
#include <hip/hip_bf16.h>

typedef unsigned int  uint;
typedef unsigned short ushort;
typedef float  f32x2  __attribute__((ext_vector_type(2)));
typedef float  f32x4  __attribute__((ext_vector_type(4)));
typedef __bf16 bf16x8 __attribute__((ext_vector_type(8)));

#define DEV static __device__ __forceinline__

DEV float  b2f(ushort b){ return __uint_as_float(((uint)b) << 16); }
DEV float  lo2f(uint u){ return __uint_as_float(u << 16); }
DEV float  hi2f(uint u){ return __uint_as_float(u & 0xffff0000u); }
DEV ushort f2b(float f){           // RNE float->bf16
  uint u = __float_as_uint(f);
  u += 0x7fffu + ((u >> 16) & 1u);
  return (ushort)(u >> 16);
}
DEV uint pk2(float a, float b){ return (uint)f2b(a) | ((uint)f2b(b) << 16); }
DEV void unpack8(uint4 v, float* f){
  f[0]=lo2f(v.x); f[1]=hi2f(v.x); f[2]=lo2f(v.y); f[3]=hi2f(v.y);
  f[4]=lo2f(v.z); f[5]=hi2f(v.z); f[6]=lo2f(v.w); f[7]=hi2f(v.w);
}
DEV int ld_idx(const void* p, int flag, long long i){
  return flag ? ((const int*)p)[i] : (int)((const long long*)p)[i];
}
DEV float ldf(const void* p, int f, int i){
  return f ? ((const float*)p)[i] : b2f(((const ushort*)p)[i]);
}
DEV int clampi(int v, int lo, int hi){ return v < lo ? lo : (v > hi ? hi : v); }

// async 16B global -> LDS (DMA).  LDS dest = wave-uniform base + lane*16.
DEV void ld16(const ushort* g, ushort* l){
  __builtin_amdgcn_global_load_lds(
      (const __attribute__((address_space(1))) void*)g,
      (__attribute__((address_space(3))) void*)l, 16, 0, 0);
}

// ---------- zero (deg+fill) + probes in one launch ----------
__global__ __launch_bounds__(256) void k_zero_probe(const uint* __restrict__ ei,
    const uint* __restrict__ xw, int* __restrict__ iflag, int* __restrict__ fflag,
    int* __restrict__ zbase, int zn){
  int i = blockIdx.x*256 + threadIdx.x;
  if (i < zn) zbase[i] = 0;
  if (blockIdx.x == 0){
    __shared__ int anyI, cntF;
    if (threadIdx.x == 0){ anyI = 0; cntF = 0; }
    __syncthreads();
    int li = 0, lc = 0;
    for (int k = threadIdx.x; k < 1024; k += 256){
      if (ei[2*k + 1] != 0u) li = 1;            // int64 => odd words all 0
      float f = fabsf(__uint_as_float(xw[k]));  // fp32 N(0,1) words decode sane
      if (f > 1e-6f && f < 1e6f) lc++;
    }
    if (li) atomicOr(&anyI, 1);
    atomicAdd(&cntF, lc);
    __syncthreads();
    if (threadIdx.x == 0){ *iflag = anyI; *fflag = (2*cntF > 1024) ? 1 : 0; }
  }
}

// ---------- CSR count + scan ----------
__global__ __launch_bounds__(256) void k_count(const void* __restrict__ ei,
    const int* __restrict__ flag, int* __restrict__ cnt, int E, int N){
  int e = blockIdx.x*256 + threadIdx.x;
  if (e >= E) return;
  int d = clampi(ld_idx(ei, *flag, (long long)E + e), 0, N-1);
  atomicAdd(&cnt[d], 1);
}

__global__ __launch_bounds__(1024) void k_scan(const int* __restrict__ deg, int* __restrict__ rp, int n){
  __shared__ int part[1024];
  int t = threadIdx.x;
  int chunk = (n + 1023) >> 10;
  int base = t * chunk;
  int s = 0;
  for (int i = 0; i < chunk; i++){ int j = base + i; if (j < n) s += deg[j]; }
  part[t] = s;
  __syncthreads();
  for (int off = 1; off < 1024; off <<= 1){
    int v = (t >= off) ? part[t - off] : 0;
    __syncthreads();
    part[t] += v;
    __syncthreads();
  }
  int run = part[t] - s;
  for (int i = 0; i < chunk; i++){ int j = base + i; if (j < n){ rp[j] = run; run += deg[j]; } }
  if (t == 1023) rp[n] = part[1023];
}

// ---------- mega: CSR-fill + weight-cvt + edge-enc + node-enc ----------
struct CvtTab { const void* src[6]; ushort* dst[6]; int n[6]; int bstart[6]; int nseg; };

__global__ __launch_bounds__(256) void k_mega(
    const void* __restrict__ ei, const int* __restrict__ iflag,
    const int* __restrict__ rp, int* __restrict__ fill, int2* __restrict__ cpair,
    CvtTab ct, const int* __restrict__ fflag,
    const void* __restrict__ ea, const void* __restrict__ eew, const void* __restrict__ eeb,
    const void* __restrict__ x, const void* __restrict__ nw, const void* __restrict__ nbias,
    float* __restrict__ eh, ushort* __restrict__ h,
    int E, int N, int FB, int CB, int EB){
  int b = blockIdx.x;
  int t = threadIdx.x;
  if (b < FB){
    // ---- CSR fill ----
    int e = b*256 + t;
    if (e >= E) return;
    int f = *iflag;
    int s = clampi(ld_idx(ei, f, e), 0, N-1);
    int d = clampi(ld_idx(ei, f, (long long)E + e), 0, N-1);
    int pos = clampi(rp[d] + atomicAdd(&fill[d], 1), 0, E-1);
    cpair[pos] = make_int2(s, e);
  } else if (b < FB + CB){
    // ---- weight conversion (w1 x3, w2 x3) ----
    int cb = b - FB;
    int s = ct.nseg - 1;
    for (int i = 1; i < ct.nseg; i++) if (cb < ct.bstart[i]){ s = i - 1; break; }
    int rel = cb - ct.bstart[s];
    const void* sp = ct.src[s];
    ushort* d = ct.dst[s];
    int f = *fflag;
    int end = ct.n[s]; int cap = rel*8192 + 8192; if (cap < end) end = cap;
    for (int i = rel*8192 + t; i < end; i += 256)
      d[i] = f ? f2b(((const float*)sp)[i]) : ((const ushort*)sp)[i];
  } else if (b < FB + CB + EB){
    // ---- edge encoder: eh = relu(ea @ eew.T + eeb), pre-unpacked f32 ----
    __shared__ float ws[128];
    __shared__ float bs[16];
    int f = *fflag;
    if (t < 128) ws[t] = ldf(eew, f, t);
    if (t < 16)  bs[t] = ldf(eeb, f, t);
    __syncthreads();
    int e = (b - FB - CB)*256 + t;
    if (e >= E) return;
    float a[8];
    if (f){
      const float4* ap = (const float4*)((const float*)ea + (size_t)e*8);
      float4 v0 = ap[0], v1 = ap[1];
      a[0]=v0.x; a[1]=v0.y; a[2]=v0.z; a[3]=v0.w;
      a[4]=v1.x; a[5]=v1.y; a[6]=v1.z; a[7]=v1.w;
    } else {
      uint4 av = *(const uint4*)((const ushort*)ea + (size_t)e*8);
      unpack8(av, a);
    }
    float o[16];
    #pragma unroll
    for (int c = 0; c < 16; c++){
      float s = bs[c];
      #pragma unroll
      for (int j = 0; j < 8; j++) s += a[j]*ws[c*8+j];
      o[c] = fmaxf(s, 0.f);
    }
    f32x4* op = (f32x4*)(eh + (size_t)e*16);
    #pragma unroll
    for (int q4 = 0; q4 < 4; q4++){
      f32x4 v = {o[q4*4+0], o[q4*4+1], o[q4*4+2], o[q4*4+3]};
      op[q4] = v;
    }
  } else {
    // ---- node encoder: h = relu(x @ nw.T + nb), 4 nodes/block ----
    __shared__ float xs[4][32];
    int f = *fflag;
    int nb = (b - FB - CB - EB)*4;
    if (t < 128){
      int ni = t >> 5, ci = t & 31;
      int n = nb + ni; if (n >= N) n = N - 1;
      xs[ni][ci] = f ? ((const float*)x)[(size_t)n*32 + ci]
                     : b2f(((const ushort*)x)[(size_t)n*32 + ci]);
    }
    __syncthreads();
    float wr[32];
    if (f){
      const float4* wp = (const float4*)((const float*)nw + (size_t)t*32);
      #pragma unroll
      for (int q4 = 0; q4 < 8; q4++){
        float4 v = wp[q4];
        wr[q4*4+0]=v.x; wr[q4*4+1]=v.y; wr[q4*4+2]=v.z; wr[q4*4+3]=v.w;
      }
    } else {
      const uint4* wp = (const uint4*)((const ushort*)nw + (size_t)t*32);
      unpack8(wp[0], wr); unpack8(wp[1], wr+8); unpack8(wp[2], wr+16); unpack8(wp[3], wr+24);
    }
    float bv = ldf(nbias, f, t);
    #pragma unroll
    for (int ni = 0; ni < 4; ni++){
      int n = nb + ni;
      if (n >= N) break;
      float s = bv;
      #pragma unroll
      for (int k = 0; k < 32; k++) s += xs[ni][k]*wr[k];
      h[(size_t)n*256 + t] = f2b(fmaxf(s, 0.f));
    }
  }
}

// ---------- LDS-staged 128x128 GEMM: P/Q producer (R9, unchanged) ----------
__global__ __launch_bounds__(256) void k_gemm_pq_lds(const ushort* __restrict__ A,
    const ushort* __restrict__ w1, int M, int Nc,
    ushort* __restrict__ P, ushort* __restrict__ Q){
  __shared__ ushort As[128*32];
  __shared__ ushort Bs[128*32];
  const int t = threadIdx.x;
  const int lane = t & 63;
  const int wv = t >> 6;
  const int m0 = blockIdx.x*128;
  const int yc = Nc >> 7;
  const int isQ = (int)blockIdx.y >= yc;
  const int n0 = (isQ ? blockIdx.y - yc : blockIdx.y)*128;
  const ushort* W = w1 + (isQ ? 256 : 0);
  ushort* C = isQ ? Q : P;
  const int lr = lane & 15;
  const int qq = lane >> 4;
  int srow0 = t >> 2,         sq0 = t & 3;
  int srow1 = (256 + t) >> 2, sq1 = t & 3;
  int ga0 = m0 + srow0; if (ga0 >= M) ga0 = M - 1;
  int ga1 = m0 + srow1; if (ga1 >= M) ga1 = M - 1;
  f32x4 acc[2][8];
  #pragma unroll
  for (int f = 0; f < 2; f++)
    #pragma unroll
    for (int j = 0; j < 8; j++) acc[f][j] = {0.f,0.f,0.f,0.f};
  for (int k0 = 0; k0 < 256; k0 += 32){
    ld16(A + (size_t)ga0*256 + k0 + sq0*8, &As[(size_t)t*8]);
    ld16(A + (size_t)ga1*256 + k0 + sq1*8, &As[(size_t)(256+t)*8]);
    ld16(W + (size_t)(n0 + srow0)*528 + k0 + sq0*8, &Bs[(size_t)t*8]);
    ld16(W + (size_t)(n0 + srow1)*528 + k0 + sq1*8, &Bs[(size_t)(256+t)*8]);
    __syncthreads();
    bf16x8 a0 = *(const bf16x8*)&As[(wv*32 + lr)*32 + qq*8];
    bf16x8 a1 = *(const bf16x8*)&As[(wv*32 + 16 + lr)*32 + qq*8];
    #pragma unroll
    for (int j = 0; j < 8; j++){
      bf16x8 b = *(const bf16x8*)&Bs[(j*16 + lr)*32 + qq*8];
      acc[0][j] = __builtin_amdgcn_mfma_f32_16x16x32_bf16(a0, b, acc[0][j], 0, 0, 0);
      acc[1][j] = __builtin_amdgcn_mfma_f32_16x16x32_bf16(a1, b, acc[1][j], 0, 0, 0);
    }
    __syncthreads();
  }
  #pragma unroll
  for (int f = 0; f < 2; f++){
    #pragma unroll
    for (int r = 0; r < 4; r++){
      int row = m0 + wv*32 + f*16 + qq*4 + r;
      if (row >= M) continue;
      #pragma unroll
      for (int j = 0; j < 8; j++)
        C[(size_t)row*Nc + n0 + j*16 + lr] = f2b(acc[f][j][r]);
    }
  }
}

// ---------- LDS-staged 64x128 GEMM + bias + deg-mask + BN + relu ----------
// Small params read raw (fp32 or bf16 via fflag).
__global__ __launch_bounds__(256) void k_gemm_bn64(const ushort* __restrict__ A, int lda,
    const ushort* __restrict__ W, int ldb, int M, int Nc, int K,
    const void* __restrict__ bias, const void* __restrict__ g, const void* __restrict__ bb,
    const void* __restrict__ rm, const void* __restrict__ rv, const int* __restrict__ fflag,
    const int* __restrict__ rp, ushort* __restrict__ H){
  __shared__ ushort As[64*32];
  __shared__ ushort Bs[128*32];
  const int t = threadIdx.x;
  const int lane = t & 63;
  const int wv = t >> 6;
  const int m0 = blockIdx.x*64;
  const int n0 = blockIdx.y*128;
  const int lr = lane & 15;
  const int qq = lane >> 4;
  int srowA = t >> 2, sqA = t & 3;
  int ga = m0 + srowA; if (ga >= M) ga = M - 1;
  int srowB0 = t >> 2,        srowB1 = 64 + (t >> 2);
  f32x4 acc[8];
  #pragma unroll
  for (int j = 0; j < 8; j++) acc[j] = {0.f,0.f,0.f,0.f};
  for (int k0 = 0; k0 < K; k0 += 32){
    ld16(A + (size_t)ga*lda + k0 + sqA*8, &As[(size_t)t*8]);
    ld16(W + (size_t)(n0 + srowB0)*ldb + k0 + sqA*8, &Bs[(size_t)t*8]);
    ld16(W + (size_t)(n0 + srowB1)*ldb + k0 + sqA*8, &Bs[(size_t)(256+t)*8]);
    __syncthreads();
    bf16x8 a = *(const bf16x8*)&As[(wv*16 + lr)*32 + qq*8];
    #pragma unroll
    for (int j = 0; j < 8; j++){
      bf16x8 b = *(const bf16x8*)&Bs[(j*16 + lr)*32 + qq*8];
      acc[j] = __builtin_amdgcn_mfma_f32_16x16x32_bf16(a, b, acc[j], 0, 0, 0);
    }
    __syncthreads();
  }
  int f = *fflag;
  float bi[8], sc[8], sh[8];
  #pragma unroll
  for (int j = 0; j < 8; j++){
    int col = n0 + j*16 + lr;
    bi[j] = ldf(bias, f, col);
    sc[j] = ldf(g, f, col) * rsqrtf(ldf(rv, f, col) + 1e-5f);
    sh[j] = ldf(bb, f, col) - ldf(rm, f, col) * sc[j];
  }
  #pragma unroll
  for (int r = 0; r < 4; r++){
    int row = m0 + wv*16 + qq*4 + r;
    if (row >= M) continue;
    int empty = (rp[row+1] - rp[row] == 0);
    #pragma unroll
    for (int j = 0; j < 8; j++){
      float v = acc[j][r] + bi[j];
      if (empty) v = 0.f;
      H[(size_t)row*Nc + n0 + j*16 + lr] = f2b(fmaxf(v*sc[j] + sh[j], 0.f));
    }
  }
}

// ---------- per-node edge aggregation (R10 known-good, b1 read raw) ----------
// 2 nodes/block, NO barriers/LDS; thread t owns channels {2t,2t+1};
// 2-edge ILP unroll.  MU may alias P (read-before-write per thread).
template<int C>
__global__ __launch_bounds__(256) void k_msg4(const ushort* P, const ushort* __restrict__ Q,
    const float* __restrict__ eh, const ushort* __restrict__ w1, const void* __restrict__ b1,
    const int* __restrict__ fflag, const int* __restrict__ rp, const int2* __restrict__ cpair,
    ushort* MU, int N){
  int t = threadIdx.x;
  int c0 = t*2;
  f32x2 wc[16];
  {
    float a0[16], a1[16];
    const uint4* wp0 = (const uint4*)(w1 + (size_t)c0*528 + 512);
    const uint4* wp1 = (const uint4*)(w1 + (size_t)(c0+1)*528 + 512);
    unpack8(wp0[0], a0); unpack8(wp0[1], a0+8);
    unpack8(wp1[0], a1); unpack8(wp1[1], a1+8);
    #pragma unroll
    for (int j = 0; j < 16; j++){ wc[j].x = a0[j]; wc[j].y = a1[j]; }
  }
  int ff = *fflag;
  f32x2 b1v = { ldf(b1, ff, c0), ldf(b1, ff, c0+1) };
  int nb = blockIdx.x*2;
  int ne = nb + 2; if (ne > N) ne = N;
  for (int n = nb; n < ne; n++){
    const int i0 = rp[n], i1 = rp[n+1];
    uint pw = *(const uint*)(P + (size_t)n*C + c0);
    f32x2 pre = { lo2f(pw) + b1v.x, hi2f(pw) + b1v.y };
    f32x2 acc0 = {0.f, 0.f}, acc1 = {0.f, 0.f};
    int i = i0;
    for (; i + 2 <= i1; i += 2){
      int2 p0 = cpair[i];
      int2 p1 = cpair[i+1];
      uint qw0 = *(const uint*)(Q + (size_t)p0.x*C + c0);
      uint qw1 = *(const uint*)(Q + (size_t)p1.x*C + c0);
      const f32x4* e0p = (const f32x4*)(eh + (size_t)p0.y*16);
      const f32x4* e1p = (const f32x4*)(eh + (size_t)p1.y*16);
      f32x4 ea0 = e0p[0], ea1 = e0p[1], ea2 = e0p[2], ea3 = e0p[3];
      f32x4 eb0 = e1p[0], eb1 = e1p[1], eb2 = e1p[2], eb3 = e1p[3];
      float ef0[16] = {ea0.x,ea0.y,ea0.z,ea0.w, ea1.x,ea1.y,ea1.z,ea1.w,
                       ea2.x,ea2.y,ea2.z,ea2.w, ea3.x,ea3.y,ea3.z,ea3.w};
      float ef1[16] = {eb0.x,eb0.y,eb0.z,eb0.w, eb1.x,eb1.y,eb1.z,eb1.w,
                       eb2.x,eb2.y,eb2.z,eb2.w, eb3.x,eb3.y,eb3.z,eb3.w};
      f32x2 d0 = { pre.x + lo2f(qw0), pre.y + hi2f(qw0) };
      f32x2 d1 = { pre.x + lo2f(qw1), pre.y + hi2f(qw1) };
      #pragma unroll
      for (int j = 0; j < 16; j++){
        f32x2 e0v = {ef0[j], ef0[j]};
        f32x2 e1v = {ef1[j], ef1[j]};
        d0 += wc[j] * e0v;
        d1 += wc[j] * e1v;
      }
      acc0.x += fmaxf(d0.x, 0.f); acc0.y += fmaxf(d0.y, 0.f);
      acc1.x += fmaxf(d1.x, 0.f); acc1.y += fmaxf(d1.y, 0.f);
    }
    if (i < i1){
      int2 p0 = cpair[i];
      uint qw0 = *(const uint*)(Q + (size_t)p0.x*C + c0);
      const f32x4* e0p = (const f32x4*)(eh + (size_t)p0.y*16);
      f32x4 ea0 = e0p[0], ea1 = e0p[1], ea2 = e0p[2], ea3 = e0p[3];
      float ef0[16] = {ea0.x,ea0.y,ea0.z,ea0.w, ea1.x,ea1.y,ea1.z,ea1.w,
                       ea2.x,ea2.y,ea2.z,ea2.w, ea3.x,ea3.y,ea3.z,ea3.w};
      f32x2 d0 = { pre.x + lo2f(qw0), pre.y + hi2f(qw0) };
      #pragma unroll
      for (int j = 0; j < 16; j++){
        f32x2 e0v = {ef0[j], ef0[j]};
        d0 += wc[j] * e0v;
      }
      acc0.x += fmaxf(d0.x, 0.f); acc0.y += fmaxf(d0.y, 0.f);
    }
    int cnt = i1 - i0;
    float inv = (cnt > 0) ? 1.f/(float)cnt : 0.f;
    *(uint*)(MU + (size_t)n*C + c0) = pk2((acc0.x + acc1.x)*inv, (acc0.y + acc1.y)*inv);
  }
}

// ---------- pooling + FC + sigmoid (all params raw) ----------
__global__ __launch_bounds__(128) void k_pool(const ushort* __restrict__ h, const void* __restrict__ batch,
    const int* __restrict__ iflag, const void* __restrict__ fw, const void* __restrict__ fb,
    const int* __restrict__ fflag, void* __restrict__ out, int N){
  int g = blockIdx.x, t = threadIdx.x;
  int ifl = *iflag;
  int lo = 0, hi = N;
  while (lo < hi){ int mid = (lo+hi) >> 1; if (ld_idx(batch, ifl, mid) <  g) lo = mid+1; else hi = mid; }
  int s0 = lo;
  hi = N;
  while (lo < hi){ int mid = (lo+hi) >> 1; if (ld_idx(batch, ifl, mid) <= g) lo = mid+1; else hi = mid; }
  int s1 = lo;
  float s = 0.f;
  for (int i = s0; i < s1; i++) s += b2f(h[(size_t)i*128 + t]);
  int cnt = s1 - s0;
  __shared__ float ps[128];
  ps[t] = s / (float)(cnt > 0 ? cnt : 1);
  __syncthreads();
  int f = *fflag;
  if (t < 12){
    float z = ldf(fb, f, t);
    for (int j = 0; j < 128; j++) z += ps[j]*ldf(fw, f, t*128 + j);
    float r = 1.f/(1.f + expf(-z));
    if (f) ((float*)out)[g*12 + t] = r;
    else   ((ushort*)out)[g*12 + t] = f2b(r);
  }
}

__global__ __launch_bounds__(256) void k_sentinel(ushort* __restrict__ out, int n){
  int i = blockIdx.x*256 + threadIdx.x;
  if (i < n) out[i] = 0x3F00;
}

extern "C" void kernel_launch(void* const* d_in, const int* in_sizes, int n_in,
                              void* d_out, int out_size, void* d_ws, size_t ws_size,
                              hipStream_t stream){
  const void* x_raw   = d_in[0];
  const void* ei_raw  = d_in[1];
  const void* ea_raw  = d_in[2];
  const void* ba_raw  = d_in[3];
  (void)n_in;

  const int N = in_sizes[3];        // 20000
  const int E = in_sizes[1] / 2;    // 200000
  const int G = out_size / 12;      // 512

  // ---- workspace plan ----
  char* base = (char*)d_ws;
  size_t off = 0;
  auto alloc = [&](size_t bytes)->char*{
    char* p = base + off;
    off = (off + bytes + 255) & ~(size_t)255;
    return p;
  };
  int* iflag    = (int*)alloc(256);
  int* fflag    = (int*)alloc(256);
  int* deg      = (int*)alloc((size_t)N*4);
  int* fill     = (int*)alloc((size_t)N*4);   // contiguous-ish after deg
  int zn        = (int)(fill - deg) + N;      // ints to zero covering both
  int* rp       = (int*)alloc((size_t)(N+1)*4);
  int2* cpair   = (int2*)alloc((size_t)E*8);
  ushort* w1c[3], *w2c[3];
  const int w1n[3] = {512*528, 512*528, 256*528};
  const int w2n[3] = {256*512, 256*512, 128*256};
  for (int i = 0; i < 3; i++) w1c[i] = (ushort*)alloc((size_t)w1n[i]*2);
  for (int i = 0; i < 3; i++) w2c[i] = (ushort*)alloc((size_t)w2n[i]*2);
  float*  e_h32 = (float*)alloc((size_t)E*16*4);    // 12.8 MB, pre-unpacked f32
  ushort* h     = (ushort*)alloc((size_t)N*256*2);
  ushort* Q     = (ushort*)alloc((size_t)N*512*2);
  ushort* PM    = (ushort*)alloc((size_t)N*512*2);

  if (off > ws_size){
    k_sentinel<<<(out_size + 255)/256, 256, 0, stream>>>((ushort*)d_out, out_size);
    return;
  }

  // ---- zero+probe, count, scan ----
  k_zero_probe<<<(zn + 255)/256, 256, 0, stream>>>((const uint*)ei_raw, (const uint*)x_raw,
                                                   iflag, fflag, deg, zn);
  k_count<<<(E + 255)/256, 256, 0, stream>>>(ei_raw, iflag, deg, E, N);
  k_scan<<<1, 1024, 0, stream>>>(deg, rp, N);

  // ---- mega: fill + weight cvt + encoders ----
  CvtTab ct; ct.nseg = 6;
  const void* csrcs[6] = {d_in[8], d_in[16], d_in[24], d_in[10], d_in[18], d_in[26]};
  ushort* cdsts[6]     = {w1c[0],  w1c[1],   w1c[2],   w2c[0],   w2c[1],   w2c[2]};
  const int cns[6]     = {w1n[0],  w1n[1],   w1n[2],   w2n[0],   w2n[1],   w2n[2]};
  int bacc = 0;
  for (int i = 0; i < 6; i++){
    ct.src[i] = csrcs[i]; ct.dst[i] = cdsts[i]; ct.n[i] = cns[i];
    ct.bstart[i] = bacc; bacc += (cns[i] + 8191)/8192;
  }
  int FB = (E + 255)/256;
  int CB = bacc;
  int EB = (E + 255)/256;
  int NB = (N + 3)/4;
  k_mega<<<FB + CB + EB + NB, 256, 0, stream>>>(
      ei_raw, iflag, rp, fill, cpair, ct, fflag,
      ea_raw, d_in[4], d_in[5], x_raw, d_in[6], d_in[7],
      e_h32, h, E, N, FB, CB, EB);

  // ---- 3 conv layers ----
  const int Cch[3] = {512, 512, 256};
  const int Od[3]  = {256, 256, 128};
  for (int i = 0; i < 3; i++){
    int di = 8 + 8*i;
    dim3 g1((N + 127)/128, 2*(Cch[i]/128));
    k_gemm_pq_lds<<<g1, 256, 0, stream>>>(h, w1c[i], N, Cch[i], PM, Q);
    dim3 gm((N + 1)/2);
    if (i < 2) k_msg4<512><<<gm, 256, 0, stream>>>(PM, Q, e_h32, w1c[i], d_in[di+1], fflag, rp, cpair, PM, N);
    else       k_msg4<256><<<gm, 128, 0, stream>>>(PM, Q, e_h32, w1c[i], d_in[di+1], fflag, rp, cpair, PM, N);
    dim3 g2((N + 63)/64, Od[i]/128 > 0 ? Od[i]/128 : 1);
    k_gemm_bn64<<<g2, 256, 0, stream>>>(PM, Cch[i], w2c[i], Cch[i], N, Od[i], Cch[i],
                                        d_in[di+3], d_in[di+4], d_in[di+5],
                                        d_in[di+6], d_in[di+7], fflag, rp, h);
  }

  // ---- mean pool + FC + sigmoid ----
  k_pool<<<G, 128, 0, stream>>>(h, ba_raw, iflag, d_in[32], d_in[33], fflag, d_out, N);
}